// Round 2
// baseline (629.162 us; speedup 1.0000x reference)
//
#include <hip/hip_runtime.h>

// ---------------------------------------------------------------------------
// AdderNet decoder: chain of L1-distance "convs" + ReLU/BN + 2x unpool.
// All intermediates live padded in d_ws: (N, C, H+2, W+4), interior at (1,1),
// borders zeroed by one hipMemsetAsync per launch. Padding contributes
// |0 - w| exactly like the reference's zero-pad.
// R2: smaller strips (more waves/CU) + ping-pong register prefetch of the
// next ci's window to hide L1/L2 latency.
// ---------------------------------------------------------------------------

__global__ __launch_bounds__(256) void pad_copy_k(
    const float* __restrict__ in, float* __restrict__ out,
    int NC, int H, int W)
{
    int i = blockIdx.x * 256 + threadIdx.x;
    int total = NC * H * W;
    if (i >= total) return;
    int w_ = i % W;
    int t  = i / W;
    int h  = t % H;
    int nc = t / H;
    int wpad = W + 4;
    out[((size_t)nc * (H + 2) + (h + 1)) * wpad + (w_ + 1)] = in[i];
}

// unpool + relu + bn fused. Non-selected positions get relu(0)*w+b = b.
__global__ __launch_bounds__(256) void unpool_k(
    const float* __restrict__ in,   // (N,C,H,W) flat
    const int*   __restrict__ locs, // (N,C,H,W) -> flat idx into (2H x 2W)
    const float* __restrict__ bw, const float* __restrict__ bb,
    float* __restrict__ out,        // padded (N,C,2H+2,2W+4)
    int C, int H, int W, int N)
{
    int i = blockIdx.x * 256 + threadIdx.x;
    int total = N * C * H * W;
    if (i >= total) return;
    int w_ = i % W;
    int t  = i / W;
    int h  = t % H; t /= H;
    int c  = t % C;
    int n  = t / C;
    float v  = in[i];
    int   id = locs[i];
    int Wo = 2 * W;
    int ho = id / Wo, wo = id % Wo;
    float scale = bw[c], bias = bb[c];
    float val = fmaxf(v, 0.f) * scale + bias;
    int wpad = Wo + 4;
    float* ob = out + (size_t)(n * C + c) * (2 * H + 2) * wpad;
    int h0 = 2 * h, w0 = 2 * w_;
#pragma unroll
    for (int dy = 0; dy < 2; ++dy)
#pragma unroll
        for (int dx = 0; dx < 2; ++dx) {
            float x = (h0 + dy == ho && w0 + dx == wo) ? val : bias;
            ob[(size_t)(h0 + dy + 1) * wpad + (w0 + dx + 1)] = x;
        }
}

template <int STRIP> struct Win { float x[3][STRIP + 2]; };

// L1-distance "adder conv". Input padded (N,CIN,H+2,W+4). Each thread computes
// a STRIP-wide horizontal strip of one output row for one (n, co).
// Ping-pong prefetch: while computing channel ci, the window for ci+1 is
// already in flight.
template <int CIN, int STRIP, bool BN, bool OUT_PADDED>
__global__ __launch_bounds__(256, 4) void adder_k(
    const float* __restrict__ xin, const float* __restrict__ w,
    const float* __restrict__ bnw, const float* __restrict__ bnb,
    float* __restrict__ out,
    int H, int W, int COUT, int SB)
{
    const int wpad = W + 4;
    int b = blockIdx.x;
    const int sb = b % SB;  b /= SB;
    const int co = b % COUT; b /= COUT;
    const int n  = b;

    const int s   = sb * 256 + (int)threadIdx.x;      // strip index
    const int spr = W / STRIP;                        // strips per row
    const int r   = s / spr;                          // output row
    const int c0  = (s - r * spr) * STRIP;            // padded col of window
    if (r >= H) return;

    const int chstride = (H + 2) * wpad;
    const float* xb = xin + (size_t)(n * CIN) * chstride + (size_t)r * wpad + c0;
    const float* wp = w + (size_t)co * CIN * 9;

    float acc[STRIP];
#pragma unroll
    for (int p = 0; p < STRIP; ++p) acc[p] = 0.f;

    auto loadw = [&](Win<STRIP>& d, int ci) {
        const float* xc = xb + (size_t)ci * chstride;
#pragma unroll
        for (int di = 0; di < 3; ++di) {
            const float* row = xc + di * wpad;        // 8B/16B aligned
            if constexpr (STRIP == 4) {
                const float4 v0 = *reinterpret_cast<const float4*>(row);
                const float2 v1 = *reinterpret_cast<const float2*>(row + 4);
                d.x[di][0] = v0.x; d.x[di][1] = v0.y; d.x[di][2] = v0.z;
                d.x[di][3] = v0.w; d.x[di][4] = v1.x; d.x[di][5] = v1.y;
            } else {
                const float2 v0 = *reinterpret_cast<const float2*>(row);
                const float2 v1 = *reinterpret_cast<const float2*>(row + 2);
                d.x[di][0] = v0.x; d.x[di][1] = v0.y;
                d.x[di][2] = v1.x; d.x[di][3] = v1.y;
            }
        }
    };

    auto compute = [&](const Win<STRIP>& d, int ci) {
        const float* wc = wp + ci * 9;
        float wv[9];
#pragma unroll
        for (int k = 0; k < 9; ++k) wv[k] = wc[k];    // wave-uniform -> s_load
#pragma unroll
        for (int di = 0; di < 3; ++di)
#pragma unroll
            for (int dj = 0; dj < 3; ++dj) {
                const float wvv = wv[di * 3 + dj];
#pragma unroll
                for (int p = 0; p < STRIP; ++p)
                    acc[p] -= fabsf(d.x[di][p + dj] - wvv); // 2 VALU/tap
            }
    };

    Win<STRIP> A, B;
    loadw(A, 0);
    for (int ci = 0; ci < CIN; ci += 2) {             // CIN is even
        loadw(B, ci + 1);
        compute(A, ci);
        loadw(A, (ci + 2 < CIN) ? ci + 2 : 0);        // harmless re-load at tail
        compute(B, ci + 1);
    }

    float scale = 1.f, bias = 0.f;
    if constexpr (BN) { scale = bnw[co]; bias = bnb[co]; }

    size_t o;
    if constexpr (OUT_PADDED)
        o = ((size_t)(n * COUT + co) * (H + 2) + (r + 1)) * wpad + (c0 + 1);
    else
        o = ((size_t)(n * COUT + co) * H + (size_t)r) * W + c0;

#pragma unroll
    for (int p = 0; p < STRIP; ++p) {
        float v = acc[p];
        if constexpr (BN) v = fmaxf(v, 0.f) * scale + bias;
        out[o + p] = v;
    }
}

// ---------------------------------------------------------------------------

extern "C" void kernel_launch(void* const* d_in, const int* in_sizes, int n_in,
                              void* d_out, int out_size, void* d_ws, size_t ws_size,
                              hipStream_t stream)
{
    const float* x      = (const float*)d_in[0];
    // d_in[1] = layer, d_in[2] = activation_idx : unused by the reference
    const int*   locs13 = (const int*)d_in[3];
    const int*   locs6  = (const int*)d_in[4];
    const float* w3  = (const float*)d_in[5];
    const float* w6  = (const float*)d_in[6];
    const float* w9  = (const float*)d_in[7];
    const float* w12 = (const float*)d_in[8];
    const float* w16 = (const float*)d_in[9];
    const float* w19 = (const float*)d_in[10];
    const float* w23 = (const float*)d_in[11];
    const float* w26 = (const float*)d_in[12];
    const float* bn5w  = (const float*)d_in[13], *bn5b  = (const float*)d_in[14];
    const float* bn8w  = (const float*)d_in[15], *bn8b  = (const float*)d_in[16];
    const float* bn11w = (const float*)d_in[17], *bn11b = (const float*)d_in[18];
    const float* bn15w = (const float*)d_in[19], *bn15b = (const float*)d_in[20];
    const float* bn18w = (const float*)d_in[21], *bn18b = (const float*)d_in[22];
    const float* bn22w = (const float*)d_in[23], *bn22b = (const float*)d_in[24];
    const float* bn25w = (const float*)d_in[25], *bn25b = (const float*)d_in[26];

    float* ws = (float*)d_ws;
    // padded buffer sizes (floats):
    //   32x32x128ch : 4*128*34*36 = 626688
    //   64x64x64ch  : 4*64*66*68  = 1148928
    //   128x128x32ch: 4*32*130*132= 2196480
    float* B0 = ws;                  // 626688
    float* B1 = ws + 626688;         // 626688
    float* B2 = ws + 1253376;        // 626688
    float* B3 = ws + 1880064;        // 1148928
    float* B4 = ws + 3028992;        // 1148928
    float* B5 = ws + 4177920;        // 2196480
    float* B6 = ws + 6374400;        // 2196480
    const size_t WS_BYTES = (size_t)8570880 * sizeof(float); // ~34.3 MB

    hipMemsetAsync(d_ws, 0, WS_BYTES, stream);

    // x -> B0 (padded)
    pad_copy_k<<<2048, 256, 0, stream>>>(x, B0, 4 * 128, 32, 32);

    // L3 : adder(x,w3) + relu + bn5          (4,128,32,32)
    adder_k<128, 2, true,  true ><<<1024, 256, 0, stream>>>(B0, w3,  bn5w,  bn5b,  B1, 32, 32, 128, 2);
    // L6 : + relu+bn8
    adder_k<128, 2, true,  true ><<<1024, 256, 0, stream>>>(B1, w6,  bn8w,  bn8b,  B2, 32, 32, 128, 2);
    // L9 : + relu+bn11
    adder_k<128, 2, true,  true ><<<1024, 256, 0, stream>>>(B2, w9,  bn11w, bn11b, B0, 32, 32, 128, 2);
    // L12: adder -> (4,64,32,32) flat (no activation before unpool)
    adder_k<128, 2, false, false><<<512, 256, 0, stream>>>(B0, w12, nullptr, nullptr, B1, 32, 32, 64, 2);
    // unpool13 + relu + bn15 -> (4,64,66,68) padded
    unpool_k<<<1024, 256, 0, stream>>>(B1, locs13, bn15w, bn15b, B3, 64, 32, 32, 4);
    // L16: + relu+bn18                       (4,64,64,64)
    adder_k<64, 4, true,  true ><<<1024, 256, 0, stream>>>(B3, w16, bn18w, bn18b, B4, 64, 64, 64, 4);
    // L19: adder -> (4,32,64,64) flat
    adder_k<64, 2, false, false><<<1024, 256, 0, stream>>>(B4, w19, nullptr, nullptr, B3, 64, 64, 32, 8);
    // unpool6 + relu + bn22 -> (4,32,130,132) padded
    unpool_k<<<2048, 256, 0, stream>>>(B3, locs6, bn22w, bn22b, B5, 32, 64, 64, 4);
    // L23: + relu+bn25                       (4,32,128,128)
    adder_k<32, 4, true,  true ><<<2048, 256, 0, stream>>>(B5, w23, bn25w, bn25b, B6, 128, 128, 32, 16);
    // L26: final adder -> d_out (4,3,128,128) flat
    adder_k<32, 2, false, false><<<384, 256, 0, stream>>>(B6, w26, nullptr, nullptr, (float*)d_out, 128, 128, 3, 32);
}

// Round 3
// 422.050 us; speedup vs baseline: 1.4907x; 1.4907x over previous
//
#include <hip/hip_runtime.h>

// ---------------------------------------------------------------------------
// AdderNet decoder. R3: register co-blocking (G output channels per thread)
// + ci-split across blocks (partials in ws + combine kernels) so every adder
// runs 512 blocks (2/CU). Window ping-pong prefetch kept.
// Padded intermediates (N,C,H+2,W+4), interior at (1,1); borders zeroed by
// one hipMemsetAsync; pad contributes |0-w| exactly like jnp.pad.
// ---------------------------------------------------------------------------

__global__ __launch_bounds__(256) void pad_copy_k(
    const float* __restrict__ in, float* __restrict__ out,
    int NC, int H, int W)
{
    int i = blockIdx.x * 256 + threadIdx.x;
    int total = NC * H * W;
    if (i >= total) return;
    int w_ = i % W;
    int t  = i / W;
    int h  = t % H;
    int nc = t / H;
    int wpad = W + 4;
    out[((size_t)nc * (H + 2) + (h + 1)) * wpad + (w_ + 1)] = in[i];
}

// unpool + relu + bn fused. Non-selected positions get relu(0)*w+b = b.
__global__ __launch_bounds__(256) void unpool_k(
    const float* __restrict__ in, const int* __restrict__ locs,
    const float* __restrict__ bw, const float* __restrict__ bb,
    float* __restrict__ out, int C, int H, int W, int N)
{
    int i = blockIdx.x * 256 + threadIdx.x;
    int total = N * C * H * W;
    if (i >= total) return;
    int w_ = i % W;
    int t  = i / W;
    int h  = t % H; t /= H;
    int c  = t % C;
    int n  = t / C;
    float v  = in[i];
    int   id = locs[i];
    int Wo = 2 * W;
    int ho = id / Wo, wo = id % Wo;
    float scale = bw[c], bias = bb[c];
    float val = fmaxf(v, 0.f) * scale + bias;
    int wpad = Wo + 4;
    float* ob = out + (size_t)(n * C + c) * (2 * H + 2) * wpad;
    int h0 = 2 * h, w0 = 2 * w_;
#pragma unroll
    for (int dy = 0; dy < 2; ++dy)
#pragma unroll
        for (int dx = 0; dx < 2; ++dx) {
            float x = (h0 + dy == ho && w0 + dx == wo) ? val : bias;
            ob[(size_t)(h0 + dy + 1) * wpad + (w0 + dx + 1)] = x;
        }
}

// sum S partials (+ optional relu+bn), write flat or padded
template <int S, bool BN, bool OUT_PADDED>
__global__ __launch_bounds__(256) void combine_k(
    const float* __restrict__ P, int pstride,
    const float* __restrict__ bw, const float* __restrict__ bb,
    float* __restrict__ out, int C, int H, int W, int total)
{
    int i = blockIdx.x * 256 + threadIdx.x;
    if (i >= total) return;
    float s = 0.f;
#pragma unroll
    for (int k = 0; k < S; ++k) s += P[(size_t)k * pstride + i];
    int w_ = i % W;
    int t  = i / W;
    int h  = t % H; t /= H;
    int c  = t % C;
    int n  = t / C;
    if constexpr (BN) s = fmaxf(s, 0.f) * bw[c] + bb[c];
    if constexpr (OUT_PADDED) {
        int wpad = W + 4;
        out[((size_t)(n * C + c) * (H + 2) + (h + 1)) * wpad + (w_ + 1)] = s;
    } else {
        out[i] = s;
    }
}

struct Win4 { float x[3][6]; };   // 3 rows x 6 cols window for STRIP=4

// L1-distance adder with G-channel register blocking and optional ci-split.
// Thread: 4-px strip of one row, G consecutive output channels, ci-chunk.
// Grid: ((n*COG + cog)*SPB + sb)*S + s.
template <int CIN, int CHUNK, int G, bool BN, bool OUT_PADDED, bool SPLIT>
__global__ __launch_bounds__(256, 2) void adder_g(
    const float* __restrict__ xin, const float* __restrict__ w,
    const float* __restrict__ bnw, const float* __restrict__ bnb,
    float* __restrict__ out,
    int H, int W, int COUT, int SPB, int S, int pstride)
{
    const int wpad = W + 4;
    const int chstride = (H + 2) * wpad;
    int b = blockIdx.x;
    const int s   = b % S;  b /= S;
    const int sb  = b % SPB; b /= SPB;
    const int cog = b % (COUT / G);
    const int n   = b / (COUT / G);
    const int co0 = cog * G;
    const int ci0 = s * CHUNK;

    const int t   = sb * 256 + (int)threadIdx.x;   // strip id (grid sized exactly)
    const int spr = W / 4;
    const int r   = t / spr;
    const int c0  = (t - r * spr) * 4;             // 16B-aligned window start

    const float* xb = xin + (size_t)n * CIN * chstride
                          + (size_t)(ci0) * chstride + (size_t)r * wpad + c0;
    const float* wp = w + ((size_t)co0 * CIN + ci0) * 9;

    float acc[G][4];
#pragma unroll
    for (int j = 0; j < G; ++j)
#pragma unroll
        for (int p = 0; p < 4; ++p) acc[j][p] = 0.f;

    auto loadw = [&](Win4& d, int ci) {
        const float* xc = xb + (size_t)ci * chstride;
#pragma unroll
        for (int di = 0; di < 3; ++di) {
            const float* row = xc + di * wpad;
            const float4 v0 = *reinterpret_cast<const float4*>(row);
            const float2 v1 = *reinterpret_cast<const float2*>(row + 4);
            d.x[di][0] = v0.x; d.x[di][1] = v0.y; d.x[di][2] = v0.z;
            d.x[di][3] = v0.w; d.x[di][4] = v1.x; d.x[di][5] = v1.y;
        }
    };

    auto compute = [&](const Win4& d, int ci) {
#pragma unroll
        for (int j = 0; j < G; ++j) {
            const float* wc = wp + ((size_t)j * CIN + ci) * 9;  // uniform -> s_load
            float wv[9];
#pragma unroll
            for (int k = 0; k < 9; ++k) wv[k] = wc[k];
#pragma unroll
            for (int di = 0; di < 3; ++di)
#pragma unroll
                for (int dj = 0; dj < 3; ++dj) {
                    const float wvv = wv[di * 3 + dj];
#pragma unroll
                    for (int p = 0; p < 4; ++p)
                        acc[j][p] -= fabsf(d.x[di][p + dj] - wvv);
                }
        }
    };

    Win4 A, B;
    loadw(A, 0);
    for (int ci = 0; ci < CHUNK; ci += 2) {          // CHUNK is even
        loadw(B, ci + 1);
        compute(A, ci);
        loadw(A, (ci + 2 < CHUNK) ? ci + 2 : 0);     // harmless tail reload
        compute(B, ci + 1);
    }

    float* op = out + (SPLIT ? (size_t)s * pstride : (size_t)0);
#pragma unroll
    for (int j = 0; j < G; ++j) {
        const int co = co0 + j;
        float scale = 1.f, bias = 0.f;
        if constexpr (BN) { scale = bnw[co]; bias = bnb[co]; }
        size_t o;
        if constexpr (OUT_PADDED)
            o = ((size_t)(n * COUT + co) * (H + 2) + (r + 1)) * wpad + (c0 + 1);
        else
            o = ((size_t)(n * COUT + co) * H + (size_t)r) * W + c0;
#pragma unroll
        for (int p = 0; p < 4; ++p) {
            float v = acc[j][p];
            if constexpr (BN) v = fmaxf(v, 0.f) * scale + bias;
            op[o + p] = v;
        }
    }
}

// ---------------------------------------------------------------------------

extern "C" void kernel_launch(void* const* d_in, const int* in_sizes, int n_in,
                              void* d_out, int out_size, void* d_ws, size_t ws_size,
                              hipStream_t stream)
{
    const float* x      = (const float*)d_in[0];
    const int*   locs13 = (const int*)d_in[3];
    const int*   locs6  = (const int*)d_in[4];
    const float* w3  = (const float*)d_in[5];
    const float* w6  = (const float*)d_in[6];
    const float* w9  = (const float*)d_in[7];
    const float* w12 = (const float*)d_in[8];
    const float* w16 = (const float*)d_in[9];
    const float* w19 = (const float*)d_in[10];
    const float* w23 = (const float*)d_in[11];
    const float* w26 = (const float*)d_in[12];
    const float* bn5w  = (const float*)d_in[13], *bn5b  = (const float*)d_in[14];
    const float* bn8w  = (const float*)d_in[15], *bn8b  = (const float*)d_in[16];
    const float* bn11w = (const float*)d_in[17], *bn11b = (const float*)d_in[18];
    const float* bn15w = (const float*)d_in[19], *bn15b = (const float*)d_in[20];
    const float* bn18w = (const float*)d_in[21], *bn18b = (const float*)d_in[22];
    const float* bn22w = (const float*)d_in[23], *bn22b = (const float*)d_in[24];
    const float* bn25w = (const float*)d_in[25], *bn25b = (const float*)d_in[26];

    float* ws = (float*)d_ws;
    // padded buffers (floats):
    float* B0 = ws;                  // 626688   (4,128,34,36)
    float* B1 = ws + 626688;         // 626688
    float* B2 = ws + 1253376;        // 626688
    float* B3 = ws + 1880064;        // 1148928  (4,64,66,68)
    float* B4 = ws + 3028992;        // 1148928
    float* B5 = ws + 4177920;        // 2196480  (4,32,130,132)
    float* B6 = ws + 6374400;        // 2196480
    // partial regions (alias dead buffers):
    float* PA = ws + 1880064;        // up to 4194304 floats (B3..B6 span, dead during L3..L12)
    float* PB = ws + 4177920;        // up to 2196480 floats (B5 region, dead during L16..L19)
    const size_t WS_BYTES = (size_t)8570880 * sizeof(float); // ~34.3 MB

    hipMemsetAsync(d_ws, 0, WS_BYTES, stream);

    pad_copy_k<<<2048, 256, 0, stream>>>(x, B0, 4 * 128, 32, 32);

    // ---- L3: 128->128 @32x32.  G=8, S=8, CHUNK=16. grid=4*16*1*8=512
    adder_g<128, 16, 8, false, false, true><<<512, 256, 0, stream>>>(
        B0, w3, nullptr, nullptr, PA, 32, 32, 128, 1, 8, 524288);
    combine_k<8, true, true><<<2048, 256, 0, stream>>>(
        PA, 524288, bn5w, bn5b, B1, 128, 32, 32, 524288);

    // ---- L6
    adder_g<128, 16, 8, false, false, true><<<512, 256, 0, stream>>>(
        B1, w6, nullptr, nullptr, PA, 32, 32, 128, 1, 8, 524288);
    combine_k<8, true, true><<<2048, 256, 0, stream>>>(
        PA, 524288, bn8w, bn8b, B2, 128, 32, 32, 524288);

    // ---- L9
    adder_g<128, 16, 8, false, false, true><<<512, 256, 0, stream>>>(
        B2, w9, nullptr, nullptr, PA, 32, 32, 128, 1, 8, 524288);
    combine_k<8, true, true><<<2048, 256, 0, stream>>>(
        PA, 524288, bn11w, bn11b, B0, 128, 32, 32, 524288);

    // ---- L12: 128->64 @32x32. G=8, S=16, CHUNK=8. grid=4*8*1*16=512
    adder_g<128, 8, 8, false, false, true><<<512, 256, 0, stream>>>(
        B0, w12, nullptr, nullptr, PA, 32, 32, 64, 1, 16, 262144);
    combine_k<16, false, false><<<1024, 256, 0, stream>>>(
        PA, 262144, nullptr, nullptr, B1, 64, 32, 32, 262144);

    // ---- unpool13 + relu + bn15 -> B3 padded (4,64,66,68)
    unpool_k<<<1024, 256, 0, stream>>>(B1, locs13, bn15w, bn15b, B3, 64, 32, 32, 4);

    // ---- L16: 64->64 @64x64. G=4, S=2, CHUNK=32. grid=4*16*4*2=512
    adder_g<64, 32, 4, false, false, true><<<512, 256, 0, stream>>>(
        B3, w16, nullptr, nullptr, PB, 64, 64, 64, 4, 2, 1048576);
    combine_k<2, true, true><<<4096, 256, 0, stream>>>(
        PB, 1048576, bn18w, bn18b, B4, 64, 64, 64, 1048576);

    // ---- L19: 64->32 @64x64. G=4, S=4, CHUNK=16. grid=4*8*4*4=512
    adder_g<64, 16, 4, false, false, true><<<512, 256, 0, stream>>>(
        B4, w19, nullptr, nullptr, PB, 64, 64, 32, 4, 4, 524288);
    combine_k<4, false, false><<<2048, 256, 0, stream>>>(
        PB, 524288, nullptr, nullptr, B3, 32, 64, 64, 524288);

    // ---- unpool6 + relu + bn22 -> B5 padded (4,32,130,132)
    unpool_k<<<2048, 256, 0, stream>>>(B3, locs6, bn22w, bn22b, B5, 32, 64, 64, 4);

    // ---- L23: 32->32 @128x128. G=4, S=1 (no split). grid=4*8*16=512
    adder_g<32, 32, 4, true, true, false><<<512, 256, 0, stream>>>(
        B5, w23, bn25w, bn25b, B6, 128, 128, 32, 16, 1, 0);

    // ---- L26: 32->3 @128x128 -> d_out flat. G=1. grid=4*3*16=192
    adder_g<32, 32, 1, false, false, false><<<192, 256, 0, stream>>>(
        B6, w26, nullptr, nullptr, (float*)d_out, 128, 128, 3, 16, 1, 0);
}